// Round 6
// baseline (267.845 us; speedup 1.0000x reference)
//
#include <hip/hip_runtime.h>
#include <math.h>

#define BB 8
#define LL 1900
#define LPAD 1920
#define EE 256
#define HH 8
#define DD 32
#define MTOK (BB*LL)              // 15200
#define SCALE 0.17677669529663687f

typedef __attribute__((ext_vector_type(8))) short bf16x8;
typedef __attribute__((ext_vector_type(4))) short bf16x4;
typedef __attribute__((ext_vector_type(4))) float floatx4;
typedef __attribute__((ext_vector_type(2))) unsigned uintx2;

__device__ inline short f2bf(float f) {
  unsigned u = __builtin_bit_cast(unsigned, f);
  u += 0x7FFF + ((u >> 16) & 1);
  return (short)(u >> 16);
}

// pack 4 fp32 -> 4 bf16 (truncate) via v_perm_b32
__device__ inline bf16x4 pack4(float s0, float s1, float s2, float s3) {
  uintx2 u;
  u.x = __builtin_amdgcn_perm(__builtin_bit_cast(unsigned, s1),
                              __builtin_bit_cast(unsigned, s0), 0x07060302u);
  u.y = __builtin_amdgcn_perm(__builtin_bit_cast(unsigned, s3),
                              __builtin_bit_cast(unsigned, s2), 0x07060302u);
  return __builtin_bit_cast(bf16x4, u);
}

// ---------------- Kernel 0: fp32 -> bf16 conversion of x, in_proj_w, out_w
#define CVT_X4  972800            // 3891200/4
#define CVT_W4  49152             // 196608/4
#define CVT_OW4 16384             // 65536/4
#define CVT_TOT (CVT_X4 + CVT_W4 + CVT_OW4)
__global__ __launch_bounds__(256) void cvt_kernel(
    const float* __restrict__ x, const float* __restrict__ w,
    const float* __restrict__ ow, short* __restrict__ xb,
    short* __restrict__ wb, short* __restrict__ owb) {
  int i = blockIdx.x * 256 + threadIdx.x;
  const float* src; short* dst; int off;
  if (i < CVT_X4) { src = x; dst = xb; off = i; }
  else if (i < CVT_X4 + CVT_W4) { src = w; dst = wb; off = i - CVT_X4; }
  else { src = ow; dst = owb; off = i - CVT_X4 - CVT_W4; }
  float4 v = *(const float4*)(src + (size_t)off * 4);
  short4 o;
  o.x = f2bf(v.x); o.y = f2bf(v.y); o.z = f2bf(v.z); o.w = f2bf(v.w);
  *(short4*)(dst + (size_t)off * 4) = o;
}

// ---------------- Kernel A: QKV projection (q pre-scaled by 1/sqrt(D)) ----
__global__ __launch_bounds__(256) void qkv_kernel(
    const short* __restrict__ x, const short* __restrict__ w,
    const float* __restrict__ bias, short* __restrict__ q,
    short* __restrict__ k, short* __restrict__ vt) {
  __shared__ short cbuf[64 * 72];
  int bid = blockIdx.x;
  int ntile = bid % 12, mtile = bid / 12;
  int wv = threadIdx.x >> 6, lane = threadIdx.x & 63;
  int l15 = lane & 15, quad = lane >> 4;

  int arow = mtile * 64 + wv * 16 + l15;
  if (arow >= MTOK) arow = MTOK - 1;
  const short* xrow = x + (size_t)arow * EE;

  floatx4 acc[4];
#pragma unroll
  for (int i = 0; i < 4; ++i) acc[i] = (floatx4){0.f, 0.f, 0.f, 0.f};

#pragma unroll
  for (int ks = 0; ks < 8; ++ks) {
    bf16x8 af = *(const bf16x8*)(xrow + ks * 32 + quad * 8);
#pragma unroll
    for (int ns = 0; ns < 4; ++ns) {
      int frow = ntile * 64 + ns * 16 + l15;
      bf16x8 bfr = *(const bf16x8*)(w + (size_t)frow * EE + ks * 32 + quad * 8);
      acc[ns] = __builtin_amdgcn_mfma_f32_16x16x32_bf16(af, bfr, acc[ns], 0, 0, 0);
    }
  }

  // C tile (64 tok x 64 f) -> LDS, +bias (+SCALE for q)
  float qs = (ntile < 4) ? SCALE : 1.0f;
#pragma unroll
  for (int ns = 0; ns < 4; ++ns) {
    float bv = bias[ntile * 64 + ns * 16 + l15];
#pragma unroll
    for (int r = 0; r < 4; ++r)
      cbuf[(wv * 16 + quad * 4 + r) * 72 + ns * 16 + l15] = f2bf((acc[ns][r] + bv) * qs);
  }
  __syncthreads();

  int t0tok = mtile * 64;
  int b0 = t0tok / LL;
  bool uni = (b0 == (t0tok + 63) / LL) && (t0tok + 63 < MTOK);
  int which = ntile >> 2;          // 0=q 1=k 2=v
  int fbase = (ntile & 3) * 64;

  if (which < 2) {
    short* dst0 = which ? k : q;
    int tl = threadIdx.x >> 2, seg = threadIdx.x & 3;
    int tok = t0tok + tl;
    if (tok < MTOK) {
      int b = uni ? b0 : tok / LL;
      int l = tok - b * LL;
      int fl = seg * 16;
      int h = (fbase + fl) >> 5;
      int d = (fbase + fl) & 31;
      size_t base = ((size_t)(b * HH + h) * LPAD + l) * DD + d;
      bf16x8 v0 = *(bf16x8*)(&cbuf[tl * 72 + fl]);
      bf16x8 v1 = *(bf16x8*)(&cbuf[tl * 72 + fl + 8]);
      *(bf16x8*)(dst0 + base) = v0;
      *(bf16x8*)(dst0 + base + 8) = v1;
    }
  } else {
    int fl = threadIdx.x >> 2, ls = threadIdx.x & 3;
    int h = (fbase + fl) >> 5;
    int d = (fbase + fl) & 31;
    if (uni) {
      int l0 = t0tok - b0 * LL + ls * 16;
      size_t base = ((size_t)(b0 * HH + h) * DD + d) * LPAD + l0;
#pragma unroll
      for (int g4 = 0; g4 < 4; ++g4) {
        int tb = ls * 16 + g4 * 4;
        short4 vv;
        vv.x = cbuf[(tb + 0) * 72 + fl];
        vv.y = cbuf[(tb + 1) * 72 + fl];
        vv.z = cbuf[(tb + 2) * 72 + fl];
        vv.w = cbuf[(tb + 3) * 72 + fl];
        *(short4*)(vt + base + g4 * 4) = vv;
      }
    } else {
#pragma unroll
      for (int i = 0; i < 16; ++i) {
        int tl = ls * 16 + i;
        int tok = t0tok + tl;
        if (tok < MTOK) {
          int b = tok / LL;
          int l = tok - b * LL;
          vt[((size_t)(b * HH + h) * DD + d) * LPAD + l] = cbuf[tl * 72 + fl];
        }
      }
    }
  }
}

// ---------------- Kernel B: flash attention (S^T trick + split-K waves) ---
// S^T = K*Q^T via mfma_16x16x16: C/D row indexing (quad*4+reg) == B-operand
// k indexing (quad*4+i), so exp(S^T) feeds straight into O^T = V^T * P^T.
// Fixed-max softmax => disjoint key sets merge by plain addition, so waves
// split the key tiles 2-ways (wave = rhalf x khalf) and merge once in LDS.
__global__ __launch_bounds__(256) void attn_kernel(
    const short* __restrict__ q, const short* __restrict__ k,
    const short* __restrict__ vt, short* __restrict__ ctx,
    const int* __restrict__ pad_size_p, const int* __restrict__ single_pad_p) {
  __shared__ float obuf[2][2][16][36];   // [rhalf][f][qrow(l15)][d] (pad 36)
  __shared__ float libuf[4][4][16];      // [rhalf*2+f][quad][l15]
  int bid = blockIdx.x;
  int bh = bid & 63, rowblk = bid >> 6;  // bh fastest -> 8 heads/XCD (L2 fit)
  int lane = threadIdx.x & 63;
  int wv = threadIdx.x >> 6;
  int rhalf = wv & 1, khalf = wv >> 1;
  int l15 = lane & 15, quad = lane >> 4;

  int ps = pad_size_p[0];
  int sp2 = 2 * single_pad_p[0];
  int t0 = ps >> 6;                      // 15

  const short* Q = q + (size_t)bh * LPAD * DD;
  const short* K = k + (size_t)bh * LPAD * DD;
  const short* VT = vt + (size_t)bh * DD * LPAD;

  int row0 = rowblk * 64 + rhalf * 32;

  // Q as B-operand frags: rows row0+f*16+l15, dims c*16+quad*4..+3
  bf16x4 qb[2][2];
#pragma unroll
  for (int f = 0; f < 2; ++f)
#pragma unroll
    for (int c = 0; c < 2; ++c)
      qb[f][c] = *(const bf16x4*)(Q + (size_t)(row0 + f * 16 + l15) * DD + c * 16 + quad * 4);

  // per-lane (qrow) visible-group window; empty for out-dn rows
  int glo[2], ghi[2];
#pragma unroll
  for (int f = 0; f < 2; ++f) {
    int row = row0 + f * 16 + l15;
    int g = row / sp2;
    int lo = g * sp2, hi = lo + sp2;
    if (row >= ps) { lo = 0; hi = 0; }
    glo[f] = lo; ghi[f] = hi;
  }

  float li[2] = {0.f, 0.f};
  floatx4 ot[2][2];                      // [frag][dblk]
#pragma unroll
  for (int f = 0; f < 2; ++f)
#pragma unroll
    for (int db = 0; db < 2; ++db) ot[f][db] = (floatx4){0.f, 0.f, 0.f, 0.f};

  auto tile = [&](int kbase, bool masked) {
    // V^T A-frags: d = db*16+l15, keys kbase+ns*16+quad*4..+3
    bf16x4 va[2][4];
#pragma unroll
    for (int db = 0; db < 2; ++db)
#pragma unroll
      for (int ns = 0; ns < 4; ++ns)
        va[db][ns] = *(const bf16x4*)(VT + (size_t)(db * 16 + l15) * LPAD + kbase + ns * 16 + quad * 4);

    bf16x4 pt[2][4];
#pragma unroll
    for (int ns = 0; ns < 4; ++ns) {
      const short* kr = K + (size_t)(kbase + ns * 16 + l15) * DD + quad * 4;
      bf16x4 ka0 = *(const bf16x4*)(kr);
      bf16x4 ka1 = *(const bf16x4*)(kr + 16);
#pragma unroll
      for (int f = 0; f < 2; ++f) {
        floatx4 st = {0.f, 0.f, 0.f, 0.f};
        st = __builtin_amdgcn_mfma_f32_16x16x16bf16_1k(ka0, qb[f][0], st, 0, 0, 0);
        st = __builtin_amdgcn_mfma_f32_16x16x16bf16_1k(ka1, qb[f][1], st, 0, 0, 0);
        float e[4];
#pragma unroll
        for (int r = 0; r < 4; ++r) {
          float ev = __expf(st[r]);
          if (masked) {
            int key = kbase + ns * 16 + quad * 4 + r;
            int vis = (key < LL) & ((key >= ps) | ((key >= glo[f]) & (key < ghi[f])));
            ev = vis ? ev : 0.f;
          }
          li[f] += ev;
          e[r] = ev;
        }
        pt[f][ns] = pack4(e[0], e[1], e[2], e[3]);
      }
    }
#pragma unroll
    for (int f = 0; f < 2; ++f)
#pragma unroll
      for (int db = 0; db < 2; ++db)
#pragma unroll
        for (int ns = 0; ns < 4; ++ns)
          ot[f][db] = __builtin_amdgcn_mfma_f32_16x16x16bf16_1k(va[db][ns], pt[f][ns], ot[f][db], 0, 0, 0);
  };

  // group tiles (cols < t0*64), alternated between the two key-half waves
  if (row0 < ps) {
    int rmaxd = row0 + 31;
    if (rmaxd >= ps) rmaxd = ps - 1;
    int c0 = (row0 / sp2) * sp2;
    int c1 = (rmaxd / sp2) * sp2 + sp2;
    if (c1 > ps) c1 = ps;
    int g_t0 = c0 >> 6;
    int g_end = (c1 + 63) >> 6;
    if (g_end > t0) g_end = t0;
    for (int jb = g_t0 + khalf; jb < g_end; jb += 2) tile(jb * 64, true);
  }
  // always-visible band [ps, LL): tiles t0..29, alternated; edges masked
  for (int jb = t0 + khalf; jb < 30; jb += 2)
    tile(jb * 64, (jb == t0) | (jb == 29));

  // ---- merge the two key-halves ----
  if (khalf == 1) {
#pragma unroll
    for (int f = 0; f < 2; ++f) {
#pragma unroll
      for (int db = 0; db < 2; ++db)
        *(floatx4*)&obuf[rhalf][f][l15][db * 16 + quad * 4] = ot[f][db];
      libuf[rhalf * 2 + f][quad][l15] = li[f];
    }
  }
  __syncthreads();
  if (khalf == 1) return;
#pragma unroll
  for (int f = 0; f < 2; ++f) {
#pragma unroll
    for (int db = 0; db < 2; ++db) {
      floatx4 t = *(floatx4*)&obuf[rhalf][f][l15][db * 16 + quad * 4];
      ot[f][db] += t;
    }
    li[f] += libuf[rhalf * 2 + f][quad][l15];
  }

  // denominator: reduce per-lane partials over the 4 quads
#pragma unroll
  for (int f = 0; f < 2; ++f) {
    li[f] += __shfl_xor(li[f], 16);
    li[f] += __shfl_xor(li[f], 32);
  }

  int b = bh >> 3, h = bh & 7;
#pragma unroll
  for (int f = 0; f < 2; ++f) {
    int row = row0 + f * 16 + l15;
    if (row >= LL) continue;
    float inv = 1.f / li[f];
    size_t base = ((size_t)b * LL + row) * EE + h * DD;
#pragma unroll
    for (int db = 0; db < 2; ++db) {
      short4 o;
      o.x = f2bf(ot[f][db][0] * inv);
      o.y = f2bf(ot[f][db][1] * inv);
      o.z = f2bf(ot[f][db][2] * inv);
      o.w = f2bf(ot[f][db][3] * inv);
      *(short4*)(ctx + base + db * 16 + quad * 4) = o;
    }
  }
}

// ---------------- Kernel C: out proj + bias + residual + LayerNorm --------
__global__ __launch_bounds__(256) void outln_kernel(
    const short* __restrict__ ctx, const short* __restrict__ ow,
    const float* __restrict__ ob, const float* __restrict__ x,
    const float* __restrict__ lg, const float* __restrict__ lb,
    float* __restrict__ out) {
  __shared__ float red[4][16][2];
  int mtile = blockIdx.x;               // 0..949, 16 rows each (exact)
  int wv = threadIdx.x >> 6, lane = threadIdx.x & 63;
  int l15 = lane & 15, quad = lane >> 4;
  int rowbase = mtile * 16;

  const short* crow = ctx + (size_t)(rowbase + l15) * EE;

  floatx4 acc[4];
#pragma unroll
  for (int i = 0; i < 4; ++i) acc[i] = (floatx4){0.f, 0.f, 0.f, 0.f};

#pragma unroll
  for (int ks = 0; ks < 8; ++ks) {
    bf16x8 af = *(const bf16x8*)(crow + ks * 32 + quad * 8);
#pragma unroll
    for (int ns = 0; ns < 4; ++ns) {
      int frow = wv * 64 + ns * 16 + l15;
      bf16x8 bfr = *(const bf16x8*)(ow + (size_t)frow * EE + ks * 32 + quad * 8);
      acc[ns] = __builtin_amdgcn_mfma_f32_16x16x32_bf16(af, bfr, acc[ns], 0, 0, 0);
    }
  }

  float obv[4], lgv[4], lbv[4];
#pragma unroll
  for (int ns = 0; ns < 4; ++ns) {
    int c = wv * 64 + ns * 16 + l15;
    obv[ns] = ob[c]; lgv[ns] = lg[c]; lbv[ns] = lb[c];
  }

  float y[4][4];                         // [ns][r]
  float s1[4] = {0.f, 0.f, 0.f, 0.f}, s2[4] = {0.f, 0.f, 0.f, 0.f};
#pragma unroll
  for (int r = 0; r < 4; ++r) {
    int tok = rowbase + quad * 4 + r;
#pragma unroll
    for (int ns = 0; ns < 4; ++ns) {
      int c = wv * 64 + ns * 16 + l15;
      float yy = acc[ns][r] + obv[ns] + x[(size_t)tok * EE + c];
      y[ns][r] = yy;
      s1[r] += yy;
      s2[r] += yy * yy;
    }
  }
#pragma unroll
  for (int r = 0; r < 4; ++r) {
#pragma unroll
    for (int off = 1; off < 16; off <<= 1) {
      s1[r] += __shfl_xor(s1[r], off, 16);
      s2[r] += __shfl_xor(s2[r], off, 16);
    }
  }
  if (l15 == 0) {
#pragma unroll
    for (int r = 0; r < 4; ++r) {
      red[wv][quad * 4 + r][0] = s1[r];
      red[wv][quad * 4 + r][1] = s2[r];
    }
  }
  __syncthreads();
#pragma unroll
  for (int r = 0; r < 4; ++r) {
    int rr = quad * 4 + r;
    float t1 = 0.f, t2 = 0.f;
#pragma unroll
    for (int w2 = 0; w2 < 4; ++w2) { t1 += red[w2][rr][0]; t2 += red[w2][rr][1]; }
    float mu = t1 * (1.f / 256.f);
    float var = t2 * (1.f / 256.f) - mu * mu;
    float rs = rsqrtf(var + 1e-5f);
    int tok = rowbase + rr;
#pragma unroll
    for (int ns = 0; ns < 4; ++ns) {
      int c = wv * 64 + ns * 16 + l15;
      out[(size_t)tok * EE + c] = (y[ns][r] - mu) * rs * lgv[ns] + lbv[ns];
    }
  }
}

extern "C" void kernel_launch(void* const* d_in, const int* in_sizes, int n_in,
                              void* d_out, int out_size, void* d_ws, size_t ws_size,
                              hipStream_t stream) {
  const float* x  = (const float*)d_in[0];
  const float* w  = (const float*)d_in[1];
  const float* wb = (const float*)d_in[2];
  const float* ow = (const float*)d_in[3];
  const float* ob = (const float*)d_in[4];
  const float* lg = (const float*)d_in[5];
  const float* lb = (const float*)d_in[6];
  const int* ps = (const int*)d_in[8];   // pad_size
  const int* sp = (const int*)d_in[9];   // single_pad

  short* xb  = (short*)d_ws;                       // 15200*256 bf16
  short* wbb = xb + (size_t)MTOK * EE;             // 768*256 bf16
  short* owb = wbb + (size_t)768 * EE;             // 256*256 bf16
  short* qw  = owb + (size_t)256 * EE;             // 64*1920*32 bf16 (pre-scaled)
  short* kw  = qw + (size_t)64 * LPAD * DD;
  short* vtw = kw + (size_t)64 * LPAD * DD;
  short* ctx = vtw + (size_t)64 * LPAD * DD;       // 15200*256 bf16

  cvt_kernel<<<CVT_TOT / 256, 256, 0, stream>>>(x, w, ow, xb, wbb, owb);
  qkv_kernel<<<238 * 12, 256, 0, stream>>>(xb, wbb, wb, qw, kw, vtw);
  attn_kernel<<<30 * 64, 256, 0, stream>>>(qw, kw, vtw, ctx, ps, sp);
  outln_kernel<<<950, 256, 0, stream>>>(ctx, owb, ob, x, lg, lb, (float*)d_out);
}

// Round 9
// 226.663 us; speedup vs baseline: 1.1817x; 1.1817x over previous
//
#include <hip/hip_runtime.h>
#include <math.h>

#define BB 8
#define LL 1900
#define LPAD 1920
#define EE 256
#define HH 8
#define DD 32
#define MTOK (BB*LL)              // 15200
#define SCALE 0.17677669529663687f

typedef __attribute__((ext_vector_type(8))) short bf16x8;
typedef __attribute__((ext_vector_type(4))) short bf16x4;
typedef __attribute__((ext_vector_type(4))) float floatx4;
typedef __attribute__((ext_vector_type(2))) unsigned uintx2;

__device__ inline short f2bf(float f) {
  unsigned u = __builtin_bit_cast(unsigned, f);
  u += 0x7FFF + ((u >> 16) & 1);
  return (short)(u >> 16);
}

// pack 4 fp32 -> 4 bf16 (truncate) via v_perm_b32
__device__ inline bf16x4 pack4(float s0, float s1, float s2, float s3) {
  uintx2 u;
  u.x = __builtin_amdgcn_perm(__builtin_bit_cast(unsigned, s1),
                              __builtin_bit_cast(unsigned, s0), 0x07060302u);
  u.y = __builtin_amdgcn_perm(__builtin_bit_cast(unsigned, s3),
                              __builtin_bit_cast(unsigned, s2), 0x07060302u);
  return __builtin_bit_cast(bf16x4, u);
}

// ---------------- Kernel 0: fp32 -> bf16 for in_proj_w, out_w only --------
#define CVT_W4  49152             // 196608/4
#define CVT_OW4 16384             // 65536/4
#define CVT_TOT (CVT_W4 + CVT_OW4)    // 65536 = 256*256
__global__ __launch_bounds__(256) void cvt_kernel(
    const float* __restrict__ w, const float* __restrict__ ow,
    short* __restrict__ wb, short* __restrict__ owb) {
  int i = blockIdx.x * 256 + threadIdx.x;
  const float* src; short* dst; int off;
  if (i < CVT_W4) { src = w; dst = wb; off = i; }
  else { src = ow; dst = owb; off = i - CVT_W4; }
  float4 v = *(const float4*)(src + (size_t)off * 4);
  short4 o;
  o.x = f2bf(v.x); o.y = f2bf(v.y); o.z = f2bf(v.z); o.w = f2bf(v.w);
  *(short4*)(dst + (size_t)off * 4) = o;
}

// ---------------- Kernel A: QKV projection (x read fp32, cvt in-register) -
__global__ __launch_bounds__(256) void qkv_kernel(
    const float* __restrict__ x, const short* __restrict__ w,
    const float* __restrict__ bias, short* __restrict__ q,
    short* __restrict__ k, short* __restrict__ vt) {
  __shared__ short cbuf[64 * 72];
  int bid = blockIdx.x;
  int ntile = bid % 12, mtile = bid / 12;
  int wv = threadIdx.x >> 6, lane = threadIdx.x & 63;
  int l15 = lane & 15, quad = lane >> 4;

  int arow = mtile * 64 + wv * 16 + l15;
  if (arow >= MTOK) arow = MTOK - 1;
  const float* xrow = x + (size_t)arow * EE;

  floatx4 acc[4];
#pragma unroll
  for (int i = 0; i < 4; ++i) acc[i] = (floatx4){0.f, 0.f, 0.f, 0.f};

#pragma unroll
  for (int ks = 0; ks < 8; ++ks) {
    float4 a0 = *(const float4*)(xrow + ks * 32 + quad * 8);
    float4 a1 = *(const float4*)(xrow + ks * 32 + quad * 8 + 4);
    bf16x8 af;
    af[0] = f2bf(a0.x); af[1] = f2bf(a0.y); af[2] = f2bf(a0.z); af[3] = f2bf(a0.w);
    af[4] = f2bf(a1.x); af[5] = f2bf(a1.y); af[6] = f2bf(a1.z); af[7] = f2bf(a1.w);
#pragma unroll
    for (int ns = 0; ns < 4; ++ns) {
      int frow = ntile * 64 + ns * 16 + l15;
      bf16x8 bfr = *(const bf16x8*)(w + (size_t)frow * EE + ks * 32 + quad * 8);
      acc[ns] = __builtin_amdgcn_mfma_f32_16x16x32_bf16(af, bfr, acc[ns], 0, 0, 0);
    }
  }

  // C tile (64 tok x 64 f) -> LDS, +bias (+SCALE for q)
  float qs = (ntile < 4) ? SCALE : 1.0f;
#pragma unroll
  for (int ns = 0; ns < 4; ++ns) {
    float bv = bias[ntile * 64 + ns * 16 + l15];
#pragma unroll
    for (int r = 0; r < 4; ++r)
      cbuf[(wv * 16 + quad * 4 + r) * 72 + ns * 16 + l15] = f2bf((acc[ns][r] + bv) * qs);
  }
  __syncthreads();

  int t0tok = mtile * 64;
  int b0 = t0tok / LL;
  bool uni = (b0 == (t0tok + 63) / LL) && (t0tok + 63 < MTOK);
  int which = ntile >> 2;          // 0=q 1=k 2=v
  int fbase = (ntile & 3) * 64;

  if (which < 2) {
    short* dst0 = which ? k : q;
    int tl = threadIdx.x >> 2, seg = threadIdx.x & 3;
    int tok = t0tok + tl;
    if (tok < MTOK) {
      int b = uni ? b0 : tok / LL;
      int l = tok - b * LL;
      int fl = seg * 16;
      int h = (fbase + fl) >> 5;
      int d = (fbase + fl) & 31;
      size_t base = ((size_t)(b * HH + h) * LPAD + l) * DD + d;
      bf16x8 v0 = *(bf16x8*)(&cbuf[tl * 72 + fl]);
      bf16x8 v1 = *(bf16x8*)(&cbuf[tl * 72 + fl + 8]);
      *(bf16x8*)(dst0 + base) = v0;
      *(bf16x8*)(dst0 + base + 8) = v1;
    }
  } else {
    int fl = threadIdx.x >> 2, ls = threadIdx.x & 3;
    int h = (fbase + fl) >> 5;
    int d = (fbase + fl) & 31;
    if (uni) {
      int l0 = t0tok - b0 * LL + ls * 16;
      size_t base = ((size_t)(b0 * HH + h) * DD + d) * LPAD + l0;
#pragma unroll
      for (int g4 = 0; g4 < 4; ++g4) {
        int tb = ls * 16 + g4 * 4;
        short4 vv;
        vv.x = cbuf[(tb + 0) * 72 + fl];
        vv.y = cbuf[(tb + 1) * 72 + fl];
        vv.z = cbuf[(tb + 2) * 72 + fl];
        vv.w = cbuf[(tb + 3) * 72 + fl];
        *(short4*)(vt + base + g4 * 4) = vv;
      }
    } else {
#pragma unroll
      for (int i = 0; i < 16; ++i) {
        int tl = ls * 16 + i;
        int tok = t0tok + tl;
        if (tok < MTOK) {
          int b = tok / LL;
          int l = tok - b * LL;
          vt[((size_t)(b * HH + h) * DD + d) * LPAD + l] = cbuf[tl * 72 + fl];
        }
      }
    }
  }
}

// ---------------- Kernel B: flash attention, LDS-staged band --------------
// S^T = K*Q^T via one mfma_16x16x32 (A=K b128 frag, B=Q b128 frag). C/D m
// index (quad*4+reg) matches the 16x16x16 PV B-operand k index, so exp(S^T)
// feeds register-only into O^T = V^T * P^T. The always-visible key band
// [t0*64, 1920) is staged chunk-wise into LDS by the whole block and shared
// by all 4 waves (128 q-rows); group tiles (<20%) read global directly.
#define VSTR 260   // vbuf stride (520 B: 8B-aligned b64 reads, bank-clean)
__global__ __launch_bounds__(256) void attn_kernel(
    const short* __restrict__ q, const short* __restrict__ k,
    const short* __restrict__ vt, short* __restrict__ ctx,
    const int* __restrict__ pad_size_p, const int* __restrict__ single_pad_p) {
  __shared__ short kbuf[256 * 40];    // [key][d], stride 40 shorts (80 B)
  __shared__ short vbuf[32 * VSTR];   // [d][key]
  int bid = blockIdx.x;
  int bh = bid & 63, rg = bid >> 6;  // bh fastest -> 8 heads/XCD (L2 fit)
  int wv = threadIdx.x >> 6, lane = threadIdx.x & 63;
  int l15 = lane & 15, quad = lane >> 4;

  int ps = pad_size_p[0];
  int sp2 = 2 * single_pad_p[0];
  int t0 = ps >> 6;                  // 15
  int kb0 = t0 * 64;                 // 960

  const short* Q = q + (size_t)bh * LPAD * DD;
  const short* K = k + (size_t)bh * LPAD * DD;
  const short* VT = vt + (size_t)bh * DD * LPAD;

  int row0 = rg * 128 + wv * 32;

  // Q as B-operand frags (16x16x32): qrow = row0+f*16+l15, dims quad*8..+7
  bf16x8 qf[2];
  qf[0] = *(const bf16x8*)(Q + (size_t)(row0 + l15) * DD + quad * 8);
  qf[1] = *(const bf16x8*)(Q + (size_t)(row0 + 16 + l15) * DD + quad * 8);

  // per-lane (qrow) visible-group window; empty for out-dn rows
  int glo[2], ghi[2];
#pragma unroll
  for (int f = 0; f < 2; ++f) {
    int row = row0 + f * 16 + l15;
    int g = row / sp2;
    int lo = g * sp2, hi = lo + sp2;
    if (row >= ps) { lo = 0; hi = 0; }
    glo[f] = lo; ghi[f] = hi;
  }

  float li[2] = {0.f, 0.f};
  floatx4 ot[2][2];                  // [frag][dblk]
#pragma unroll
  for (int f = 0; f < 2; ++f)
#pragma unroll
    for (int db = 0; db < 2; ++db) ot[f][db] = (floatx4){0.f, 0.f, 0.f, 0.f};

  // ---- group phase: keys < kb0, direct global loads -----------------------
  if (row0 < ps) {
    int rmaxd = row0 + 31;
    if (rmaxd >= ps) rmaxd = ps - 1;
    int c0 = (row0 / sp2) * sp2;
    int c1 = (rmaxd / sp2) * sp2 + sp2;
    if (c1 > ps) c1 = ps;
    int g_t0 = c0 >> 6;
    int g_end = (c1 + 63) >> 6;
    if (g_end > t0) g_end = t0;
    for (int jb = g_t0; jb < g_end; ++jb) {
      int kbase = jb * 64;
      bf16x4 va[2][4];
#pragma unroll
      for (int db = 0; db < 2; ++db)
#pragma unroll
        for (int ns = 0; ns < 4; ++ns)
          va[db][ns] = *(const bf16x4*)(VT + (size_t)(db * 16 + l15) * LPAD + kbase + ns * 16 + quad * 4);
      bf16x4 pt[2][4];
#pragma unroll
      for (int ns = 0; ns < 4; ++ns) {
        bf16x8 ka = *(const bf16x8*)(K + (size_t)(kbase + ns * 16 + l15) * DD + quad * 8);
#pragma unroll
        for (int f = 0; f < 2; ++f) {
          floatx4 z = {0.f, 0.f, 0.f, 0.f};
          floatx4 st = __builtin_amdgcn_mfma_f32_16x16x32_bf16(ka, qf[f], z, 0, 0, 0);
          float e[4];
#pragma unroll
          for (int r = 0; r < 4; ++r) {
            int key = kbase + ns * 16 + quad * 4 + r;
            int vis = (key >= glo[f]) & (key < ghi[f]);
            float ev = vis ? __expf(st[r]) : 0.f;
            li[f] += ev;
            e[r] = ev;
          }
          pt[f][ns] = pack4(e[0], e[1], e[2], e[3]);
        }
      }
#pragma unroll
      for (int f = 0; f < 2; ++f)
#pragma unroll
        for (int db = 0; db < 2; ++db)
#pragma unroll
          for (int ns = 0; ns < 4; ++ns)
            ot[f][db] = __builtin_amdgcn_mfma_f32_16x16x16bf16_1k(va[db][ns], pt[f][ns], ot[f][db], 0, 0, 0);
    }
  }

  // ---- band phase: keys [kb0, LPAD), staged chunk-wise into LDS -----------
  for (int kbase = kb0; kbase < LPAD; kbase += 256) {
    int nk = LPAD - kbase; if (nk > 256) nk = 256;
    // stage K: nk rows x 32 d, four 8-short segments per row
    for (int t = threadIdx.x; t < nk * 4; t += 256) {
      int key = t >> 2, seg = t & 3;
      *(bf16x8*)&kbuf[key * 40 + seg * 8] =
          *(const bf16x8*)(K + (size_t)(kbase + key) * DD + seg * 8);
    }
    // stage V^T: 32 d x nk keys, 8-key segments
    for (int t = threadIdx.x; t < 1024; t += 256) {
      int d = t >> 5, s = t & 31;
      if (s * 8 < nk)
        *(bf16x8*)&vbuf[d * VSTR + s * 8] =
            *(const bf16x8*)(VT + (size_t)d * LPAD + kbase + s * 8);
    }
    __syncthreads();
    int ntiles = nk >> 6;
    for (int t = 0; t < ntiles; ++t) {
      int tk0 = kbase + t * 64;
      bool masked = (tk0 < ps) | (tk0 + 64 > LL);   // group-edge OR tail
      int tl = t * 64;
      bf16x4 va[2][4];
#pragma unroll
      for (int db = 0; db < 2; ++db)
#pragma unroll
        for (int ns = 0; ns < 4; ++ns)
          va[db][ns] = *(const bf16x4*)&vbuf[(db * 16 + l15) * VSTR + tl + ns * 16 + quad * 4];
      bf16x4 pt[2][4];
#pragma unroll
      for (int ns = 0; ns < 4; ++ns) {
        bf16x8 ka = *(const bf16x8*)&kbuf[(tl + ns * 16 + l15) * 40 + quad * 8];
#pragma unroll
        for (int f = 0; f < 2; ++f) {
          floatx4 z = {0.f, 0.f, 0.f, 0.f};
          floatx4 st = __builtin_amdgcn_mfma_f32_16x16x32_bf16(ka, qf[f], z, 0, 0, 0);
          float e[4];
#pragma unroll
          for (int r = 0; r < 4; ++r) {
            float ev = __expf(st[r]);
            if (masked) {
              int key = tk0 + ns * 16 + quad * 4 + r;
              int vis = (key < LL) & ((key >= ps) | ((key >= glo[f]) & (key < ghi[f])));
              ev = vis ? ev : 0.f;
            }
            li[f] += ev;
            e[r] = ev;
          }
          pt[f][ns] = pack4(e[0], e[1], e[2], e[3]);
        }
      }
#pragma unroll
      for (int f = 0; f < 2; ++f)
#pragma unroll
        for (int db = 0; db < 2; ++db)
#pragma unroll
          for (int ns = 0; ns < 4; ++ns)
            ot[f][db] = __builtin_amdgcn_mfma_f32_16x16x16bf16_1k(va[db][ns], pt[f][ns], ot[f][db], 0, 0, 0);
    }
    __syncthreads();
  }

  // denominator: reduce per-lane partials over the 4 quads
#pragma unroll
  for (int f = 0; f < 2; ++f) {
    li[f] += __shfl_xor(li[f], 16);
    li[f] += __shfl_xor(li[f], 32);
  }

  int b = bh >> 3, h = bh & 7;
#pragma unroll
  for (int f = 0; f < 2; ++f) {
    int row = row0 + f * 16 + l15;
    if (row >= LL) continue;
    float inv = 1.f / li[f];
    size_t base = ((size_t)b * LL + row) * EE + h * DD;
#pragma unroll
    for (int db = 0; db < 2; ++db) {
      short4 o;
      o.x = f2bf(ot[f][db][0] * inv);
      o.y = f2bf(ot[f][db][1] * inv);
      o.z = f2bf(ot[f][db][2] * inv);
      o.w = f2bf(ot[f][db][3] * inv);
      *(short4*)(ctx + base + db * 16 + quad * 4) = o;
    }
  }
}

// ---------------- Kernel C: out proj + bias + residual + LayerNorm --------
__global__ __launch_bounds__(256) void outln_kernel(
    const short* __restrict__ ctx, const short* __restrict__ ow,
    const float* __restrict__ ob, const float* __restrict__ x,
    const float* __restrict__ lg, const float* __restrict__ lb,
    float* __restrict__ out) {
  __shared__ float red[4][16][2];
  int mtile = blockIdx.x;               // 0..949, 16 rows each (exact)
  int wv = threadIdx.x >> 6, lane = threadIdx.x & 63;
  int l15 = lane & 15, quad = lane >> 4;
  int rowbase = mtile * 16;

  const short* crow = ctx + (size_t)(rowbase + l15) * EE;

  floatx4 acc[4];
#pragma unroll
  for (int i = 0; i < 4; ++i) acc[i] = (floatx4){0.f, 0.f, 0.f, 0.f};

#pragma unroll
  for (int ks = 0; ks < 8; ++ks) {
    bf16x8 af = *(const bf16x8*)(crow + ks * 32 + quad * 8);
#pragma unroll
    for (int ns = 0; ns < 4; ++ns) {
      int frow = wv * 64 + ns * 16 + l15;
      bf16x8 bfr = *(const bf16x8*)(ow + (size_t)frow * EE + ks * 32 + quad * 8);
      acc[ns] = __builtin_amdgcn_mfma_f32_16x16x32_bf16(af, bfr, acc[ns], 0, 0, 0);
    }
  }

  float obv[4], lgv[4], lbv[4];
#pragma unroll
  for (int ns = 0; ns < 4; ++ns) {
    int c = wv * 64 + ns * 16 + l15;
    obv[ns] = ob[c]; lgv[ns] = lg[c]; lbv[ns] = lb[c];
  }

  float y[4][4];                         // [ns][r]
  float s1[4] = {0.f, 0.f, 0.f, 0.f}, s2[4] = {0.f, 0.f, 0.f, 0.f};
#pragma unroll
  for (int r = 0; r < 4; ++r) {
    int tok = rowbase + quad * 4 + r;
#pragma unroll
    for (int ns = 0; ns < 4; ++ns) {
      int c = wv * 64 + ns * 16 + l15;
      float yy = acc[ns][r] + obv[ns] + x[(size_t)tok * EE + c];
      y[ns][r] = yy;
      s1[r] += yy;
      s2[r] += yy * yy;
    }
  }
#pragma unroll
  for (int r = 0; r < 4; ++r) {
#pragma unroll
    for (int off = 1; off < 16; off <<= 1) {
      s1[r] += __shfl_xor(s1[r], off, 16);
      s2[r] += __shfl_xor(s2[r], off, 16);
    }
  }
  if (l15 == 0) {
#pragma unroll
    for (int r = 0; r < 4; ++r) {
      red[wv][quad * 4 + r][0] = s1[r];
      red[wv][quad * 4 + r][1] = s2[r];
    }
  }
  __syncthreads();
#pragma unroll
  for (int r = 0; r < 4; ++r) {
    int rr = quad * 4 + r;
    float t1 = 0.f, t2 = 0.f;
#pragma unroll
    for (int w2 = 0; w2 < 4; ++w2) { t1 += red[w2][rr][0]; t2 += red[w2][rr][1]; }
    float mu = t1 * (1.f / 256.f);
    float var = t2 * (1.f / 256.f) - mu * mu;
    float rs = rsqrtf(var + 1e-5f);
    int tok = rowbase + rr;
#pragma unroll
    for (int ns = 0; ns < 4; ++ns) {
      int c = wv * 64 + ns * 16 + l15;
      out[(size_t)tok * EE + c] = (y[ns][r] - mu) * rs * lgv[ns] + lbv[ns];
    }
  }
}

extern "C" void kernel_launch(void* const* d_in, const int* in_sizes, int n_in,
                              void* d_out, int out_size, void* d_ws, size_t ws_size,
                              hipStream_t stream) {
  const float* x  = (const float*)d_in[0];
  const float* w  = (const float*)d_in[1];
  const float* wb = (const float*)d_in[2];
  const float* ow = (const float*)d_in[3];
  const float* ob = (const float*)d_in[4];
  const float* lg = (const float*)d_in[5];
  const float* lb = (const float*)d_in[6];
  const int* ps = (const int*)d_in[8];   // pad_size
  const int* sp = (const int*)d_in[9];   // single_pad

  short* wbb = (short*)d_ws;                       // 768*256 bf16
  short* owb = wbb + (size_t)768 * EE;             // 256*256 bf16
  short* qw  = owb + (size_t)256 * EE;             // 64*1920*32 bf16 (pre-scaled)
  short* kw  = qw + (size_t)64 * LPAD * DD;
  short* vtw = kw + (size_t)64 * LPAD * DD;
  short* ctx = vtw + (size_t)64 * LPAD * DD;       // 15200*256 bf16

  cvt_kernel<<<CVT_TOT / 256, 256, 0, stream>>>(w, ow, wbb, owb);
  qkv_kernel<<<238 * 12, 256, 0, stream>>>(x, wbb, wb, qw, kw, vtw);
  attn_kernel<<<15 * 64, 256, 0, stream>>>(qw, kw, vtw, ctx, ps, sp);
  outln_kernel<<<950, 256, 0, stream>>>(ctx, owb, ob, x, lg, lb, (float*)d_out);
}

// Round 10
// 225.697 us; speedup vs baseline: 1.1867x; 1.0043x over previous
//
#include <hip/hip_runtime.h>
#include <math.h>

#define BB 8
#define LL 1900
#define LPAD 1920
#define EE 256
#define HH 8
#define DD 32
#define MTOK (BB*LL)              // 15200
#define SCALE 0.17677669529663687f

typedef __attribute__((ext_vector_type(8))) short bf16x8;
typedef __attribute__((ext_vector_type(4))) short bf16x4;
typedef __attribute__((ext_vector_type(4))) float floatx4;
typedef __attribute__((ext_vector_type(2))) unsigned uintx2;

__device__ inline short f2bf(float f) {
  unsigned u = __builtin_bit_cast(unsigned, f);
  u += 0x7FFF + ((u >> 16) & 1);
  return (short)(u >> 16);
}

// pack 4 fp32 -> 4 bf16 (truncate) via v_perm_b32
__device__ inline bf16x4 pack4(float s0, float s1, float s2, float s3) {
  uintx2 u;
  u.x = __builtin_amdgcn_perm(__builtin_bit_cast(unsigned, s1),
                              __builtin_bit_cast(unsigned, s0), 0x07060302u);
  u.y = __builtin_amdgcn_perm(__builtin_bit_cast(unsigned, s3),
                              __builtin_bit_cast(unsigned, s2), 0x07060302u);
  return __builtin_bit_cast(bf16x4, u);
}

// ---------------- Kernel 0: fp32 -> bf16 for in_proj_w, out_w only --------
#define CVT_W4  49152             // 196608/4
#define CVT_OW4 16384             // 65536/4
#define CVT_TOT (CVT_W4 + CVT_OW4)    // 65536 = 256*256
__global__ __launch_bounds__(256) void cvt_kernel(
    const float* __restrict__ w, const float* __restrict__ ow,
    short* __restrict__ wb, short* __restrict__ owb) {
  int i = blockIdx.x * 256 + threadIdx.x;
  const float* src; short* dst; int off;
  if (i < CVT_W4) { src = w; dst = wb; off = i; }
  else { src = ow; dst = owb; off = i - CVT_W4; }
  float4 v = *(const float4*)(src + (size_t)off * 4);
  short4 o;
  o.x = f2bf(v.x); o.y = f2bf(v.y); o.z = f2bf(v.z); o.w = f2bf(v.w);
  *(short4*)(dst + (size_t)off * 4) = o;
}

// ---------------- Kernel A: QKV projection (XCD-affine grid) --------------
// mtile padded to 240 (multiple of 8) and made the FAST grid index, so the
// 12 ntile passes over one x-tile all land on XCD = mtile%8 and hit its L2.
__global__ __launch_bounds__(256) void qkv_kernel(
    const float* __restrict__ x, const short* __restrict__ w,
    const float* __restrict__ bias, short* __restrict__ q,
    short* __restrict__ k, short* __restrict__ vt) {
  __shared__ short cbuf[64 * 72];
  int bid = blockIdx.x;
  int mtile = bid % 240, ntile = bid / 240;
  if (mtile >= 238) return;
  int wv = threadIdx.x >> 6, lane = threadIdx.x & 63;
  int l15 = lane & 15, quad = lane >> 4;

  int arow = mtile * 64 + wv * 16 + l15;
  if (arow >= MTOK) arow = MTOK - 1;
  const float* xrow = x + (size_t)arow * EE;

  floatx4 acc[4];
#pragma unroll
  for (int i = 0; i < 4; ++i) acc[i] = (floatx4){0.f, 0.f, 0.f, 0.f};

#pragma unroll
  for (int ks = 0; ks < 8; ++ks) {
    float4 a0 = *(const float4*)(xrow + ks * 32 + quad * 8);
    float4 a1 = *(const float4*)(xrow + ks * 32 + quad * 8 + 4);
    bf16x8 af;
    af[0] = f2bf(a0.x); af[1] = f2bf(a0.y); af[2] = f2bf(a0.z); af[3] = f2bf(a0.w);
    af[4] = f2bf(a1.x); af[5] = f2bf(a1.y); af[6] = f2bf(a1.z); af[7] = f2bf(a1.w);
#pragma unroll
    for (int ns = 0; ns < 4; ++ns) {
      int frow = ntile * 64 + ns * 16 + l15;
      bf16x8 bfr = *(const bf16x8*)(w + (size_t)frow * EE + ks * 32 + quad * 8);
      acc[ns] = __builtin_amdgcn_mfma_f32_16x16x32_bf16(af, bfr, acc[ns], 0, 0, 0);
    }
  }

  // C tile (64 tok x 64 f) -> LDS, +bias (+SCALE for q)
  float qs = (ntile < 4) ? SCALE : 1.0f;
#pragma unroll
  for (int ns = 0; ns < 4; ++ns) {
    float bv = bias[ntile * 64 + ns * 16 + l15];
#pragma unroll
    for (int r = 0; r < 4; ++r)
      cbuf[(wv * 16 + quad * 4 + r) * 72 + ns * 16 + l15] = f2bf((acc[ns][r] + bv) * qs);
  }
  __syncthreads();

  int t0tok = mtile * 64;
  int b0 = t0tok / LL;
  bool uni = (b0 == (t0tok + 63) / LL) && (t0tok + 63 < MTOK);
  int which = ntile >> 2;          // 0=q 1=k 2=v
  int fbase = (ntile & 3) * 64;

  if (which < 2) {
    short* dst0 = which ? k : q;
    int tl = threadIdx.x >> 2, seg = threadIdx.x & 3;
    int tok = t0tok + tl;
    if (tok < MTOK) {
      int b = uni ? b0 : tok / LL;
      int l = tok - b * LL;
      int fl = seg * 16;
      int h = (fbase + fl) >> 5;
      int d = (fbase + fl) & 31;
      size_t base = ((size_t)(b * HH + h) * LPAD + l) * DD + d;
      bf16x8 v0 = *(bf16x8*)(&cbuf[tl * 72 + fl]);
      bf16x8 v1 = *(bf16x8*)(&cbuf[tl * 72 + fl + 8]);
      *(bf16x8*)(dst0 + base) = v0;
      *(bf16x8*)(dst0 + base + 8) = v1;
    }
  } else {
    int fl = threadIdx.x >> 2, ls = threadIdx.x & 3;
    int h = (fbase + fl) >> 5;
    int d = (fbase + fl) & 31;
    if (uni) {
      int l0 = t0tok - b0 * LL + ls * 16;
      size_t base = ((size_t)(b0 * HH + h) * DD + d) * LPAD + l0;
#pragma unroll
      for (int g4 = 0; g4 < 4; ++g4) {
        int tb = ls * 16 + g4 * 4;
        short4 vv;
        vv.x = cbuf[(tb + 0) * 72 + fl];
        vv.y = cbuf[(tb + 1) * 72 + fl];
        vv.z = cbuf[(tb + 2) * 72 + fl];
        vv.w = cbuf[(tb + 3) * 72 + fl];
        *(short4*)(vt + base + g4 * 4) = vv;
      }
    } else {
#pragma unroll
      for (int i = 0; i < 16; ++i) {
        int tl = ls * 16 + i;
        int tok = t0tok + tl;
        if (tok < MTOK) {
          int b = tok / LL;
          int l = tok - b * LL;
          vt[((size_t)(b * HH + h) * DD + d) * LPAD + l] = cbuf[tl * 72 + fl];
        }
      }
    }
  }
}

// ---------------- Kernel B: flash attention, LDS-staged band --------------
// S^T = K*Q^T via one mfma_16x16x32 (A=K b128 frag, B=Q b128 frag). C/D m
// index (quad*4+reg) matches the 16x16x16 PV B-operand k index, so exp(S^T)
// feeds register-only into O^T = V^T * P^T. The always-visible key band
// [t0*64, 1920) is staged chunk-wise into LDS by the whole block and shared
// by all 4 waves (128 q-rows); group tiles (<20%) read global directly.
#define VSTR 260   // vbuf stride (520 B: 8B-aligned b64 reads, bank-clean)
__global__ __launch_bounds__(256) void attn_kernel(
    const short* __restrict__ q, const short* __restrict__ k,
    const short* __restrict__ vt, short* __restrict__ ctx,
    const int* __restrict__ pad_size_p, const int* __restrict__ single_pad_p) {
  __shared__ short kbuf[256 * 40];    // [key][d], stride 40 shorts (80 B)
  __shared__ short vbuf[32 * VSTR];   // [d][key]
  int bid = blockIdx.x;
  int bh = bid & 63, rg = bid >> 6;  // bh fastest -> 8 heads/XCD (L2 fit)
  int wv = threadIdx.x >> 6, lane = threadIdx.x & 63;
  int l15 = lane & 15, quad = lane >> 4;

  int ps = pad_size_p[0];
  int sp2 = 2 * single_pad_p[0];
  int t0 = ps >> 6;                  // 15
  int kb0 = t0 * 64;                 // 960

  const short* Q = q + (size_t)bh * LPAD * DD;
  const short* K = k + (size_t)bh * LPAD * DD;
  const short* VT = vt + (size_t)bh * DD * LPAD;

  int row0 = rg * 128 + wv * 32;

  // Q as B-operand frags (16x16x32): qrow = row0+f*16+l15, dims quad*8..+7
  bf16x8 qf[2];
  qf[0] = *(const bf16x8*)(Q + (size_t)(row0 + l15) * DD + quad * 8);
  qf[1] = *(const bf16x8*)(Q + (size_t)(row0 + 16 + l15) * DD + quad * 8);

  // per-lane (qrow) visible-group window; empty for out-dn rows
  int glo[2], ghi[2];
#pragma unroll
  for (int f = 0; f < 2; ++f) {
    int row = row0 + f * 16 + l15;
    int g = row / sp2;
    int lo = g * sp2, hi = lo + sp2;
    if (row >= ps) { lo = 0; hi = 0; }
    glo[f] = lo; ghi[f] = hi;
  }

  float li[2] = {0.f, 0.f};
  floatx4 ot[2][2];                  // [frag][dblk]
#pragma unroll
  for (int f = 0; f < 2; ++f)
#pragma unroll
    for (int db = 0; db < 2; ++db) ot[f][db] = (floatx4){0.f, 0.f, 0.f, 0.f};

  // ---- group phase: keys < kb0, direct global loads -----------------------
  if (row0 < ps) {
    int rmaxd = row0 + 31;
    if (rmaxd >= ps) rmaxd = ps - 1;
    int c0 = (row0 / sp2) * sp2;
    int c1 = (rmaxd / sp2) * sp2 + sp2;
    if (c1 > ps) c1 = ps;
    int g_t0 = c0 >> 6;
    int g_end = (c1 + 63) >> 6;
    if (g_end > t0) g_end = t0;
    for (int jb = g_t0; jb < g_end; ++jb) {
      int kbase = jb * 64;
      bf16x4 va[2][4];
#pragma unroll
      for (int db = 0; db < 2; ++db)
#pragma unroll
        for (int ns = 0; ns < 4; ++ns)
          va[db][ns] = *(const bf16x4*)(VT + (size_t)(db * 16 + l15) * LPAD + kbase + ns * 16 + quad * 4);
      bf16x4 pt[2][4];
#pragma unroll
      for (int ns = 0; ns < 4; ++ns) {
        bf16x8 ka = *(const bf16x8*)(K + (size_t)(kbase + ns * 16 + l15) * DD + quad * 8);
#pragma unroll
        for (int f = 0; f < 2; ++f) {
          floatx4 z = {0.f, 0.f, 0.f, 0.f};
          floatx4 st = __builtin_amdgcn_mfma_f32_16x16x32_bf16(ka, qf[f], z, 0, 0, 0);
          float e[4];
#pragma unroll
          for (int r = 0; r < 4; ++r) {
            int key = kbase + ns * 16 + quad * 4 + r;
            int vis = (key >= glo[f]) & (key < ghi[f]);
            float ev = vis ? __expf(st[r]) : 0.f;
            li[f] += ev;
            e[r] = ev;
          }
          pt[f][ns] = pack4(e[0], e[1], e[2], e[3]);
        }
      }
#pragma unroll
      for (int f = 0; f < 2; ++f)
#pragma unroll
        for (int db = 0; db < 2; ++db)
#pragma unroll
          for (int ns = 0; ns < 4; ++ns)
            ot[f][db] = __builtin_amdgcn_mfma_f32_16x16x16bf16_1k(va[db][ns], pt[f][ns], ot[f][db], 0, 0, 0);
    }
  }

  // ---- band phase: keys [kb0, LPAD), staged chunk-wise into LDS -----------
  for (int kbase = kb0; kbase < LPAD; kbase += 256) {
    int nk = LPAD - kbase; if (nk > 256) nk = 256;
    // stage K: nk rows x 32 d, four 8-short segments per row
    for (int t = threadIdx.x; t < nk * 4; t += 256) {
      int key = t >> 2, seg = t & 3;
      *(bf16x8*)&kbuf[key * 40 + seg * 8] =
          *(const bf16x8*)(K + (size_t)(kbase + key) * DD + seg * 8);
    }
    // stage V^T: 32 d x nk keys, 8-key segments
    for (int t = threadIdx.x; t < 1024; t += 256) {
      int d = t >> 5, s = t & 31;
      if (s * 8 < nk)
        *(bf16x8*)&vbuf[d * VSTR + s * 8] =
            *(const bf16x8*)(VT + (size_t)d * LPAD + kbase + s * 8);
    }
    __syncthreads();
    int ntiles = nk >> 6;
    for (int t = 0; t < ntiles; ++t) {
      int tk0 = kbase + t * 64;
      bool masked = (tk0 < ps) | (tk0 + 64 > LL);   // group-edge OR tail
      int tl = t * 64;
      bf16x4 va[2][4];
#pragma unroll
      for (int db = 0; db < 2; ++db)
#pragma unroll
        for (int ns = 0; ns < 4; ++ns)
          va[db][ns] = *(const bf16x4*)&vbuf[(db * 16 + l15) * VSTR + tl + ns * 16 + quad * 4];
      bf16x4 pt[2][4];
#pragma unroll
      for (int ns = 0; ns < 4; ++ns) {
        bf16x8 ka = *(const bf16x8*)&kbuf[(tl + ns * 16 + l15) * 40 + quad * 8];
#pragma unroll
        for (int f = 0; f < 2; ++f) {
          floatx4 z = {0.f, 0.f, 0.f, 0.f};
          floatx4 st = __builtin_amdgcn_mfma_f32_16x16x32_bf16(ka, qf[f], z, 0, 0, 0);
          float e[4];
#pragma unroll
          for (int r = 0; r < 4; ++r) {
            float ev = __expf(st[r]);
            if (masked) {
              int key = tk0 + ns * 16 + quad * 4 + r;
              int vis = (key < LL) & ((key >= ps) | ((key >= glo[f]) & (key < ghi[f])));
              ev = vis ? ev : 0.f;
            }
            li[f] += ev;
            e[r] = ev;
          }
          pt[f][ns] = pack4(e[0], e[1], e[2], e[3]);
        }
      }
#pragma unroll
      for (int f = 0; f < 2; ++f)
#pragma unroll
        for (int db = 0; db < 2; ++db)
#pragma unroll
          for (int ns = 0; ns < 4; ++ns)
            ot[f][db] = __builtin_amdgcn_mfma_f32_16x16x16bf16_1k(va[db][ns], pt[f][ns], ot[f][db], 0, 0, 0);
    }
    __syncthreads();
  }

  // denominator: reduce per-lane partials over the 4 quads
#pragma unroll
  for (int f = 0; f < 2; ++f) {
    li[f] += __shfl_xor(li[f], 16);
    li[f] += __shfl_xor(li[f], 32);
  }

  int b = bh >> 3, h = bh & 7;
#pragma unroll
  for (int f = 0; f < 2; ++f) {
    int row = row0 + f * 16 + l15;
    if (row >= LL) continue;
    float inv = 1.f / li[f];
    size_t base = ((size_t)b * LL + row) * EE + h * DD;
#pragma unroll
    for (int db = 0; db < 2; ++db) {
      short4 o;
      o.x = f2bf(ot[f][db][0] * inv);
      o.y = f2bf(ot[f][db][1] * inv);
      o.z = f2bf(ot[f][db][2] * inv);
      o.w = f2bf(ot[f][db][3] * inv);
      *(short4*)(ctx + base + db * 16 + quad * 4) = o;
    }
  }
}

// ---------------- Kernel C: out proj + bias + residual + LayerNorm --------
__global__ __launch_bounds__(256) void outln_kernel(
    const short* __restrict__ ctx, const short* __restrict__ ow,
    const float* __restrict__ ob, const float* __restrict__ x,
    const float* __restrict__ lg, const float* __restrict__ lb,
    float* __restrict__ out) {
  __shared__ float red[4][16][2];
  int mtile = blockIdx.x;               // 0..949, 16 rows each (exact)
  int wv = threadIdx.x >> 6, lane = threadIdx.x & 63;
  int l15 = lane & 15, quad = lane >> 4;
  int rowbase = mtile * 16;

  const short* crow = ctx + (size_t)(rowbase + l15) * EE;

  floatx4 acc[4];
#pragma unroll
  for (int i = 0; i < 4; ++i) acc[i] = (floatx4){0.f, 0.f, 0.f, 0.f};

#pragma unroll
  for (int ks = 0; ks < 8; ++ks) {
    bf16x8 af = *(const bf16x8*)(crow + ks * 32 + quad * 8);
#pragma unroll
    for (int ns = 0; ns < 4; ++ns) {
      int frow = wv * 64 + ns * 16 + l15;
      bf16x8 bfr = *(const bf16x8*)(ow + (size_t)frow * EE + ks * 32 + quad * 8);
      acc[ns] = __builtin_amdgcn_mfma_f32_16x16x32_bf16(af, bfr, acc[ns], 0, 0, 0);
    }
  }

  float obv[4], lgv[4], lbv[4];
#pragma unroll
  for (int ns = 0; ns < 4; ++ns) {
    int c = wv * 64 + ns * 16 + l15;
    obv[ns] = ob[c]; lgv[ns] = lg[c]; lbv[ns] = lb[c];
  }

  float y[4][4];                         // [ns][r]
  float s1[4] = {0.f, 0.f, 0.f, 0.f}, s2[4] = {0.f, 0.f, 0.f, 0.f};
#pragma unroll
  for (int r = 0; r < 4; ++r) {
    int tok = rowbase + quad * 4 + r;
#pragma unroll
    for (int ns = 0; ns < 4; ++ns) {
      int c = wv * 64 + ns * 16 + l15;
      float yy = acc[ns][r] + obv[ns] + x[(size_t)tok * EE + c];
      y[ns][r] = yy;
      s1[r] += yy;
      s2[r] += yy * yy;
    }
  }
#pragma unroll
  for (int r = 0; r < 4; ++r) {
#pragma unroll
    for (int off = 1; off < 16; off <<= 1) {
      s1[r] += __shfl_xor(s1[r], off, 16);
      s2[r] += __shfl_xor(s2[r], off, 16);
    }
  }
  if (l15 == 0) {
#pragma unroll
    for (int r = 0; r < 4; ++r) {
      red[wv][quad * 4 + r][0] = s1[r];
      red[wv][quad * 4 + r][1] = s2[r];
    }
  }
  __syncthreads();
#pragma unroll
  for (int r = 0; r < 4; ++r) {
    int rr = quad * 4 + r;
    float t1 = 0.f, t2 = 0.f;
#pragma unroll
    for (int w2 = 0; w2 < 4; ++w2) { t1 += red[w2][rr][0]; t2 += red[w2][rr][1]; }
    float mu = t1 * (1.f / 256.f);
    float var = t2 * (1.f / 256.f) - mu * mu;
    float rs = rsqrtf(var + 1e-5f);
    int tok = rowbase + rr;
#pragma unroll
    for (int ns = 0; ns < 4; ++ns) {
      int c = wv * 64 + ns * 16 + l15;
      out[(size_t)tok * EE + c] = (y[ns][r] - mu) * rs * lgv[ns] + lbv[ns];
    }
  }
}

extern "C" void kernel_launch(void* const* d_in, const int* in_sizes, int n_in,
                              void* d_out, int out_size, void* d_ws, size_t ws_size,
                              hipStream_t stream) {
  const float* x  = (const float*)d_in[0];
  const float* w  = (const float*)d_in[1];
  const float* wb = (const float*)d_in[2];
  const float* ow = (const float*)d_in[3];
  const float* ob = (const float*)d_in[4];
  const float* lg = (const float*)d_in[5];
  const float* lb = (const float*)d_in[6];
  const int* ps = (const int*)d_in[8];   // pad_size
  const int* sp = (const int*)d_in[9];   // single_pad

  short* wbb = (short*)d_ws;                       // 768*256 bf16
  short* owb = wbb + (size_t)768 * EE;             // 256*256 bf16
  short* qw  = owb + (size_t)256 * EE;             // 64*1920*32 bf16 (pre-scaled)
  short* kw  = qw + (size_t)64 * LPAD * DD;
  short* vtw = kw + (size_t)64 * LPAD * DD;
  short* ctx = vtw + (size_t)64 * LPAD * DD;       // 15200*256 bf16

  cvt_kernel<<<CVT_TOT / 256, 256, 0, stream>>>(w, ow, wbb, owb);
  qkv_kernel<<<240 * 12, 256, 0, stream>>>(x, wbb, wb, qw, kw, vtw);
  attn_kernel<<<15 * 64, 256, 0, stream>>>(qw, kw, vtw, ctx, ps, sp);
  outln_kernel<<<950, 256, 0, stream>>>(ctx, owb, ob, x, lg, lb, (float*)d_out);
}